// Round 9
// baseline (122.773 us; speedup 1.0000x reference)
//
#include <hip/hip_runtime.h>
#include <hip/hip_bf16.h>

// Problem constants
#define NQ 8192            // B*S flattened tokens
#define DIM 64             // embed dim
#define SPLITS 32          // key-dimension split (partials merged by kernel 3)
#define QBLK 256           // queries per block (4 waves x 64)
#define WQ 64              // queries per wave
#define BN 64              // keys per tile
#define KEYS_PER_SPLIT (NQ / SPLITS)       // 256
#define NTILES (KEYS_PER_SPLIT / BN)       // 4
#define GRID_FLASH ((NQ / QBLK) * SPLITS)  // 1024
#define MERGEB 256         // merge grid
#define MROWS (NQ / MERGEB)                // 32 rows per merge block
#define SC2 0.51012301920911057f           // (1/sqrt(8)) * log2(e), folded into qq
#define KSTR 72            // LDS row stride in shorts (qkv/merge weight tiles)

typedef short s8v __attribute__((ext_vector_type(8)));   // 8 x bf16 bits
typedef short s4v __attribute__((ext_vector_type(4)));   // 4 x bf16 bits
typedef float f4v __attribute__((ext_vector_type(4)));
typedef int   i4v __attribute__((ext_vector_type(4)));

__device__ __forceinline__ float b2f(short s) {
  unsigned int u = ((unsigned int)(unsigned short)s) << 16;
  return __uint_as_float(u);
}
__device__ __forceinline__ short f2b(float f) {
  __hip_bfloat16 h = __float2bfloat16(f);
  return *reinterpret_cast<short*>(&h);
}
__device__ __forceinline__ int pack_bf16x2(float a, float b) {
  union { __hip_bfloat162 h; int i; } u;
  u.h = __float22bfloat162_rn(make_float2(a, b));
  return u.i;
}
__device__ __forceinline__ float fast_exp2(float x) {
#if __has_builtin(__builtin_amdgcn_exp2f)
  return __builtin_amdgcn_exp2f(x);   // single v_exp_f32, no OCML call
#else
  return exp2f(x);
#endif
}

// ---------------- QKV projection + quantum map (fp32 in, bf16 out) ----------
// q_q[n,e] = SC2 * cos(theta[e]) * cos( sum_d x[n,d]*W[e,d] + b[e] )  [SC2
// folded: flash applies exp2 directly to the MFMA score].
// K and V go to kvT in FRAGMENT-LINEAR TILED order (8192 shorts per 64-key
// tile: 8 K-chunks then 8 V-chunks of 512 = chunk*512 + lane*8 + j), so flash
// stages tiles with linear conflict-free DMA and reads fragments with zero
// repack. V chunks bake in the K=32 PV key permutation.
#define QROWS 16
__global__ __launch_bounds__(256) void qkv_kernel(
    const float* __restrict__ x,
    const float* __restrict__ wq, const float* __restrict__ bq,
    const float* __restrict__ wk, const float* __restrict__ bk,
    const float* __restrict__ wv, const float* __restrict__ bv,
    const float* __restrict__ theta,
    short* __restrict__ qq, short* __restrict__ kvT) {
  __shared__ __align__(16) short wsh[3][DIM][KSTR];  // bf16 weights
  __shared__ __align__(16) short xsb[QROWS][DIM];    // bf16 x rows
  int tid = threadIdx.x;
  for (int i = tid; i < 3 * DIM * 16; i += 256) {
    int m = i >> 10;
    int rem = i & 1023;
    int r = rem >> 4, c4 = (rem & 15) << 2;
    const float* src = (m == 0) ? wq : (m == 1) ? wk : wv;
    float4 w = *(const float4*)&src[r * DIM + c4];
    s4v p = {f2b(w.x), f2b(w.y), f2b(w.z), f2b(w.w)};
    *(s4v*)&wsh[m][r][c4] = p;
  }
  int rowbase = blockIdx.x * QROWS;
  for (int i = tid; i < QROWS * 16; i += 256) {
    int r = i >> 4, c4 = (i & 15) << 2;
    float4 v = *(const float4*)&x[(rowbase + r) * DIM + c4];
    s4v p = {f2b(v.x), f2b(v.y), f2b(v.z), f2b(v.w)};
    *(s4v*)&xsb[r][c4] = p;
  }
  __syncthreads();
  int e = tid & 63, rg = tid >> 6;
  float ct = __cosf(theta[e]);
  float bqv = bq[e], bkv = bk[e], bvv = bv[e];
  for (int r = rg; r < QROWS; r += 4) {
    float aq = bqv, ak = bkv, av = bvv;
#pragma unroll
    for (int c8 = 0; c8 < 8; ++c8) {
      s8v xv = *(const s8v*)&xsb[r][c8 * 8];
      s8v w0 = *(const s8v*)&wsh[0][e][c8 * 8];
      s8v w1 = *(const s8v*)&wsh[1][e][c8 * 8];
      s8v w2 = *(const s8v*)&wsh[2][e][c8 * 8];
#pragma unroll
      for (int j = 0; j < 8; ++j) {
        float xf = b2f(xv[j]);
        aq += xf * b2f(w0[j]);
        ak += xf * b2f(w1[j]);
        av += xf * b2f(w2[j]);
      }
    }
    int n = rowbase + r;
    qq[n * DIM + e] = f2b(SC2 * ct * __cosf(aq));
    size_t tb = (size_t)(n >> 6) * 8192;
    kvT[tb + ((n & 63) >> 4) * 1024 + (e >> 5) * 512 +
        ((e & 31) >> 3) * 128 + (n & 15) * 8 + (e & 7)] = f2b(ct * __cosf(ak));
    kvT[tb + 4096 + ((n & 32) >> 5) * 2048 + (e >> 4) * 512 +
        ((n & 15) >> 2) * 128 + (e & 15) * 8 +
        ((n & 3) | ((n & 16) >> 2))] = f2b(ct * __cosf(av));
  }
}

// ---------------- Flash attention (no-max streaming softmax) ----------------
// |s| <= 64/sqrt(8) = 22.6 -> exp(s) <= 6.6e9, row sums <= 5.5e13: fp32-safe,
// so no running max; split partials merge by pure summation.
// QK computed as S^T (A=K, B=Q): exp'd C-regs are directly a PV A-operand.
// PV uses K=32 MFMA with the key-perm baked into kvT's V chunks.
// Row sums via MFMA against an all-ones B fragment (no VALU adds/shuffles).
// 4 waves/block share each staged tile (staging traffic halved vs 2-wave);
// SPLITS=32 keeps grid at 1024 = 4 blocks x 16 waves per CU.
#if __has_builtin(__builtin_amdgcn_global_load_lds)
#define DMA_CHUNK(srcp, dstp) \
  __builtin_amdgcn_global_load_lds( \
      (const __attribute__((address_space(1))) void*)(srcp), \
      (__attribute__((address_space(3))) void*)(dstp), 16, 0, 0)
#else
#define DMA_CHUNK(srcp, dstp) \
  { *(s8v*)((short*)(dstp) + (threadIdx.x & 63) * 8) = \
        *(const s8v*)((const short*)(srcp)); }
#endif

__global__ __launch_bounds__(256, 2) void flash_kernel(
    const short* __restrict__ qq, const short* __restrict__ kvT,
    short* __restrict__ pO, short* __restrict__ pL) {
  __shared__ __align__(16) short lds[2][8192];  // dbuf: 8 K + 8 V chunks

  int tid = threadIdx.x;
  int wave = tid >> 6, lane = tid & 63;
  int l15 = lane & 15, quad = lane >> 4;
  int qblock = blockIdx.x >> 5, split = blockIdx.x & 31;
  int qbase = qblock * QBLK + wave * WQ;

  // Q B-frags: B[n=query=l15][k=dim=quad*8+j], two k-halves, 4 q-subtiles
  s8v qf[4][2];
#pragma unroll
  for (int qt = 0; qt < 4; ++qt) {
    const short* qr = qq + (qbase + qt * 16 + l15) * DIM + quad * 8;
    qf[qt][0] = *(const s8v*)qr;
    qf[qt][1] = *(const s8v*)(qr + 32);
  }

  const short ONE = (short)0x3F80;  // bf16 1.0
  const s8v ones = {ONE, ONE, ONE, ONE, ONE, ONE, ONE, ONE};

  f4v o[4][4], ol[4];
#pragma unroll
  for (int qt = 0; qt < 4; ++qt) {
    ol[qt] = (f4v){0.f, 0.f, 0.f, 0.f};
#pragma unroll
    for (int c = 0; c < 4; ++c) o[qt][c] = (f4v){0.f, 0.f, 0.f, 0.f};
  }

  int gt0 = split * NTILES;  // first global 64-key tile of this split

  // each of the 4 waves stages 4 of the 16 chunks (2 KB per wave)
#define STAGE(T, BUF)                                                        \
  {                                                                          \
    const short* s_ = kvT + (size_t)(gt0 + (T)) * 8192 + wave * 2048 +       \
                      lane * 8;                                              \
    short* d_ = &lds[BUF][wave * 2048];                                      \
    _Pragma("unroll") for (int c2 = 0; c2 < 4; ++c2)                         \
        DMA_CHUNK(s_ + c2 * 512, d_ + c2 * 512);                             \
  }

  STAGE(0, 0)

  for (int t = 0; t < NTILES; ++t) {
    __syncthreads();  // buf t&1 staged; buf (t+1)&1 fully consumed
    if (t + 1 < NTILES) STAGE(t + 1, (t + 1) & 1)

    const short* kb = lds[t & 1];
    const short* vb = lds[t & 1] + 4096;

#pragma unroll
    for (int kp = 0; kp < 2; ++kp) {   // pair of 16-key sub-tiles
      i4v pai[4];                      // exp'd P, A-operand bits, per qt
#pragma unroll
      for (int h = 0; h < 2; ++h) {
        int kt = kp * 2 + h;
        s8v kf0 = *(const s8v*)&kb[(kt * 2) * 512 + lane * 8];
        s8v kf1 = *(const s8v*)&kb[(kt * 2 + 1) * 512 + lane * 8];
#pragma unroll
        for (int qt = 0; qt < 4; ++qt) {
          f4v acc = (f4v){0.f, 0.f, 0.f, 0.f};
          acc = __builtin_amdgcn_mfma_f32_16x16x32_bf16(kf0, qf[qt][0], acc, 0, 0, 0);
          acc = __builtin_amdgcn_mfma_f32_16x16x32_bf16(kf1, qf[qt][1], acc, 0, 0, 0);
          // acc[r] = SC2*S^T[key=kt*16+quad*4+r][query=qt*16+l15]
          pai[qt][h * 2]     = pack_bf16x2(fast_exp2(acc[0]), fast_exp2(acc[1]));
          pai[qt][h * 2 + 1] = pack_bf16x2(fast_exp2(acc[2]), fast_exp2(acc[3]));
        }
      }
      // row sums via MFMA against ones (accumulates ol; all cols identical)
#pragma unroll
      for (int qt = 0; qt < 4; ++qt)
        ol[qt] = __builtin_amdgcn_mfma_f32_16x16x32_bf16(
            __builtin_bit_cast(s8v, pai[qt]), ones, ol[qt], 0, 0, 0);
#pragma unroll
      for (int c = 0; c < 4; ++c) {
        s8v vf = *(const s8v*)&vb[(kp * 4 + c) * 512 + lane * 8];
#pragma unroll
        for (int qt = 0; qt < 4; ++qt)
          o[qt][c] = __builtin_amdgcn_mfma_f32_16x16x32_bf16(
              __builtin_bit_cast(s8v, pai[qt]), vf, o[qt][c], 0, 0, 0);
      }
    }
  }

  // store bf16 partials: pO[q][split][e] (merge-friendly), pL[q][split]
#pragma unroll
  for (int qt = 0; qt < 4; ++qt) {
#pragma unroll
    for (int r = 0; r < 4; ++r) {
      int q = qbase + qt * 16 + quad * 4 + r;
      short* dst = pO + (size_t)q * (SPLITS * DIM) + split * DIM;
#pragma unroll
      for (int c = 0; c < 4; ++c) dst[c * 16 + l15] = f2b(o[qt][c][r]);
      if (l15 == 0) pL[(size_t)q * SPLITS + split] = f2b(ol[qt][r]);
    }
  }
}

// ---------------- merge partials + output projection (fp32 out) -------------
__global__ __launch_bounds__(256) void merge_kernel(
    const short* __restrict__ pO, const short* __restrict__ pL,
    const float* __restrict__ wo, const float* __restrict__ bo,
    float* __restrict__ out) {
  __shared__ __align__(16) short wsh[DIM * KSTR];
  __shared__ __align__(16) float att[MROWS * DIM];
  int tid = threadIdx.x;
  int q0 = blockIdx.x * MROWS;
  for (int i = tid; i < DIM * 16; i += 256) {
    int r = i >> 4, c4 = (i & 15) << 2;
    float4 w = *(const float4*)&wo[r * DIM + c4];
    s4v p = {f2b(w.x), f2b(w.y), f2b(w.z), f2b(w.w)};
    *(s4v*)&wsh[r * KSTR + c4] = p;
  }
  int wave = tid >> 6, j = tid & 63;
  // phase 1: att rows. Row = SPLITS*DIM = 2048 shorts. Sweep s: lane j holds
  // sp = s*8 + (j>>3), e = (j&7)*8 + m; xor-tree over bits 3..5 completes sp.
#pragma unroll
  for (int i = 0; i < MROWS / 4; ++i) {
    int rr = wave * (MROWS / 4) + i;
    int q = q0 + rr;
    const short* prow = pO + (size_t)q * (SPLITS * DIM);
    float a[8] = {0.f, 0.f, 0.f, 0.f, 0.f, 0.f, 0.f, 0.f};
#pragma unroll
    for (int s = 0; s < 4; ++s) {
      s8v v = *(const s8v*)&prow[s * 512 + j * 8];
#pragma unroll
      for (int m = 0; m < 8; ++m) a[m] += b2f(v[m]);
    }
    // pL: lane j covers sp in [(j>>3)*4, +4)
    s4v lv = *(const s4v*)&pL[(size_t)q * SPLITS + (j >> 3) * 4];
    float l = b2f(lv[0]) + b2f(lv[1]) + b2f(lv[2]) + b2f(lv[3]);
#pragma unroll
    for (int st = 8; st < 64; st <<= 1) {
      l += __shfl_xor(l, st);
#pragma unroll
      for (int m = 0; m < 8; ++m) a[m] += __shfl_xor(a[m], st);
    }
#if __has_builtin(__builtin_amdgcn_rcpf)
    float ri = __builtin_amdgcn_rcpf(l);
#else
    float ri = 1.f / l;
#endif
    if (j < 8) {
      float4 f0 = {a[0] * ri, a[1] * ri, a[2] * ri, a[3] * ri};
      float4 f1 = {a[4] * ri, a[5] * ri, a[6] * ri, a[7] * ri};
      *(float4*)&att[rr * DIM + j * 8] = f0;
      *(float4*)&att[rr * DIM + j * 8 + 4] = f1;
    }
  }
  __syncthreads();
  int e = tid & 63, rg = tid >> 6;
  for (int rr = rg; rr < MROWS; rr += 4) {
    float acc = bo[e];
#pragma unroll
    for (int c8 = 0; c8 < 8; ++c8) {
      s8v w = *(const s8v*)&wsh[e * KSTR + c8 * 8];
      const float* ar = &att[rr * DIM + c8 * 8];
      acc += ar[0] * b2f(w[0]) + ar[1] * b2f(w[1]) + ar[2] * b2f(w[2]) + ar[3] * b2f(w[3])
           + ar[4] * b2f(w[4]) + ar[5] * b2f(w[5]) + ar[6] * b2f(w[6]) + ar[7] * b2f(w[7]);
    }
    out[(size_t)(q0 + rr) * DIM + e] = acc;
  }
}

extern "C" void kernel_launch(void* const* d_in, const int* in_sizes, int n_in,
                              void* d_out, int out_size, void* d_ws, size_t ws_size,
                              hipStream_t stream) {
  const float* x  = (const float*)d_in[0];
  const float* wq = (const float*)d_in[1];
  const float* bq = (const float*)d_in[2];
  const float* wk = (const float*)d_in[3];
  const float* bk = (const float*)d_in[4];
  const float* wv = (const float*)d_in[5];
  const float* bv = (const float*)d_in[6];
  const float* th = (const float*)d_in[7];
  const float* wo = (const float*)d_in[8];
  const float* bo = (const float*)d_in[9];

  char* ws = (char*)d_ws;
  short* qq  = (short*)(ws);                            // 1 MB  (Q, SC2-scaled)
  short* kvT = (short*)(ws + (1u << 20));               // 2 MB  (K+V frag-tiled)
  short* pO  = (short*)(ws + (3u << 20));               // 32 MB bf16 partials [q][sp][e]
  short* pL  = (short*)(ws + (35u << 20));              // 512 KB bf16 sums [q][sp]

  hipLaunchKernelGGL(qkv_kernel, dim3(NQ / QROWS), dim3(256), 0, stream,
                     x, wq, bq, wk, bk, wv, bv, th, qq, kvT);
  hipLaunchKernelGGL(flash_kernel, dim3(GRID_FLASH), dim3(256), 0, stream,
                     qq, kvT, pO, pL);
  hipLaunchKernelGGL(merge_kernel, dim3(MERGEB), dim3(256), 0, stream,
                     pO, pL, wo, bo, (float*)d_out);
}